// Round 1
// baseline (2661.536 us; speedup 1.0000x reference)
//
#include <hip/hip_runtime.h>
#include <math.h>

#define Hh 360
#define Ww 720
#define Cc 64
#define Bb 2
#define HW (Hh*Ww)
#define NBINS 361   // rfft bins 0..360
#define SCALE 0.037267799624996496f  // 1/sqrt(720)

// ---------------------------------------------------------------- twiddles
__global__ __launch_bounds__(256) void init_tw_kernel(float2* __restrict__ tw) {
    int k = blockIdx.x * 256 + threadIdx.x;
    if (k < Ww) {
        double a = (6.283185307179586476925286766559 * (double)k) / (double)Ww;
        tw[k] = make_float2((float)cos(a), (float)sin(a));
    }
}

// ------------------------------------------------------------- row starts
// rows[] is sorted; rs[h] = first t with rows[t]==h, rs[360]=T.
__global__ __launch_bounds__(256) void row_starts_kernel(const int* __restrict__ rows,
                                                         int T, int* __restrict__ rs) {
    int h = blockIdx.x * 256 + threadIdx.x;
    if (h > Hh) return;
    if (h == Hh) { rs[Hh] = T; return; }
    int lo = 0, hi = T;
    while (lo < hi) {
        int mid = (lo + hi) >> 1;
        if (rows[mid] < h) lo = mid + 1; else hi = mid;
    }
    rs[h] = lo;
}

// ------------------------------------------------------- forward partial DFT
// X[j] = (1/sqrt(720)) * sum_w x[w] e^{-2pi i j w/720}, only j = 0..count-1.
// Pairing w <-> 720-w: Re = sum_{w=0}^{360} xp[w] cos(jw th), Im = -sum xq[w] sin(jw th)
__global__ __launch_bounds__(256) void fwd_dft_kernel(
    const float* __restrict__ x, const float2* __restrict__ tw,
    const int* __restrict__ rs, float* __restrict__ xm_r,
    float* __restrict__ xm_i, int T)
{
    __shared__ float2 xpq[16][NBINS];
    __shared__ float2 twl[Ww];
    const int h = blockIdx.x;
    const int bcBase = blockIdx.y * 16;
    const int tid = threadIdx.x;
    const int tstart = rs[h];
    const int count = rs[h + 1] - tstart;
    for (int i = tid; i < Ww; i += 256) twl[i] = tw[i];
    for (int idx = tid; idx < 16 * NBINS; idx += 256) {
        int bcl = idx / NBINS;
        int w = idx - bcl * NBINS;
        const float* row = x + (size_t)(bcBase + bcl) * HW + h * Ww;
        float a = row[w];
        float p, q;
        if (w == 0 || w == Ww / 2) { p = a; q = 0.0f; }
        else { float b2 = row[Ww - w]; p = a + b2; q = a - b2; }
        xpq[bcl][w] = make_float2(p, q);
    }
    __syncthreads();
    const int bcl = tid >> 4;
    const int jl = tid & 15;
    float* outr = xm_r + (size_t)(bcBase + bcl) * T + tstart;
    float* outi = xm_i + (size_t)(bcBase + bcl) * T + tstart;
    for (int j = jl; j < count; j += 16) {
        float re = 0.f, im = 0.f;
        int idx = 0;
#pragma unroll 4
        for (int w = 0; w < NBINS; ++w) {
            float2 pq = xpq[bcl][w];
            float2 t = twl[idx];
            re = fmaf(pq.x, t.x, re);
            im = fmaf(pq.y, t.y, im);
            idx += j;
            idx = (idx >= Ww) ? idx - Ww : idx;
        }
        outr[j] = re * SCALE;
        outi[j] = -im * SCALE;
    }
}

// ------------------------------------------------------------ middle stage
__device__ __forceinline__ float gelu_exact(float v) {
    return 0.5f * v * (1.0f + erff(v * 0.7071067811865476f));
}

__global__ __launch_bounds__(256) void middle_kernel(
    float* __restrict__ xm_r, float* __restrict__ xm_i,
    const float* __restrict__ mean_r, const float* __restrict__ mean_i,
    const float* __restrict__ stdv,
    const float* __restrict__ mags_r, const float* __restrict__ mags_i,
    const float* __restrict__ bias_r, const float* __restrict__ bias_i,
    const float* __restrict__ w1_r, const float* __restrict__ w1_i,
    const float* __restrict__ brelu_p,
    const float* __restrict__ w2_r, const float* __restrict__ w2_i,
    const float* __restrict__ glu_mags, const float* __restrict__ glu_phases,
    int T, int nTile)
{
    __shared__ float2 W1[64 * 65];   // [i][o] transposed, pad 65
    __shared__ float2 W2[64 * 65];
    __shared__ float2 hbuf[4][64];
    __shared__ float2 h2buf[4][64];
    const int tid = threadIdx.x;
    const int b = blockIdx.x / nTile;
    const int tile = blockIdx.x - b * nTile;
    const int t0 = tile * 32;
    for (int idx = tid; idx < 4096; idx += 256) {
        int i = idx & 63;
        int o = idx >> 6;
        W1[i * 65 + o] = make_float2(w1_r[o * 64 + i], w1_i[o * 64 + i]);
        W2[i * 65 + o] = make_float2(w2_r[o * 64 + i], w2_i[o * 64 + i]);
    }
    const float brelu = brelu_p[0];
    const int o = tid & 63;
    const int tl = tid >> 6;
    __syncthreads();
    for (int tt = 0; tt < 32; tt += 4) {
        const int t = t0 + tt + tl;
        const bool valid = (t < T);
        float xr = 0.f, xi = 0.f;
        float2 h1 = make_float2(0.f, 0.f);
        if (valid) {
            size_t xidx = ((size_t)(b * Cc + o)) * T + t;
            xr = xm_r[xidx]; xi = xm_i[xidx];
            float inv = 1.0f / (1e-12f + stdv[t]);
            float hr = (xr - mean_r[t]) * inv;
            float hi2 = (xi - mean_i[t]) * inv;
            float mr = mags_r[o], mi = mags_i[o];
            h1.x = fmaf(hr, mr, fmaf(-hi2, mi, bias_r[o]));
            h1.y = fmaf(hr, mi, fmaf(hi2, mr, bias_i[o]));
        }
        hbuf[tl][o] = h1;
        __syncthreads();
        float ar = 0.f, ai = 0.f;
#pragma unroll 8
        for (int i = 0; i < 64; ++i) {
            float2 wv = W1[i * 65 + o];
            float2 hv = hbuf[tl][i];
            ar = fmaf(wv.x, hv.x, ar); ar = fmaf(-wv.y, hv.y, ar);
            ai = fmaf(wv.x, hv.y, ai); ai = fmaf(wv.y, hv.x, ai);
        }
        float r = sqrtf(ar * ar + ai * ai);
        float g = gelu_exact(r + brelu);
        float2 h2;
        if (r > 0.f) { float f = g / r; h2 = make_float2(f * ar, f * ai); }
        else h2 = make_float2(g, 0.f);
        h2buf[tl][o] = h2;
        __syncthreads();
        float cr = 0.f, ci = 0.f;
#pragma unroll 8
        for (int i = 0; i < 64; ++i) {
            float2 wv = W2[i * 65 + o];
            float2 hv = h2buf[tl][i];
            cr = fmaf(wv.x, hv.x, cr); cr = fmaf(-wv.y, hv.y, cr);
            ci = fmaf(wv.x, hv.y, ci); ci = fmaf(wv.y, hv.x, ci);
        }
        if (valid) {
            size_t xidx = ((size_t)(b * Cc + o)) * T + t;
            float r3 = sqrtf(cr * cr + ci * ci);
            float gm = glu_mags[(size_t)o * T + t];
            float gp = glu_phases[(size_t)o * T + t];
            float sg = 1.0f / (1.0f + expf(-(r3 + gm)));
            float ux, uy;
            if (r3 > 0.f) { float ir3 = 1.0f / r3; ux = cr * ir3; uy = ci * ir3; }
            else { ux = 1.f; uy = 0.f; }
            float sp, cp;
            sincosf(gp, &sp, &cp);
            float gx = sg * (ux * cp - uy * sp);
            float gy = sg * (ux * sp + uy * cp);
            xm_r[xidx] = xr * gx - xi * gy;
            xm_i[xidx] = xr * gy + xi * gx;
        }
    }
}

// ------------------------------------------------------- inverse sparse DFT
// y[w] = s*( Re X0 + [nyq*(-1)^w] + 2*sum_{j>=1}(Re Xj cos(jw th) - Im Xj sin(jw th)) )
// computed as output pairs (w, 720-w): cos same, sin negated.
__global__ __launch_bounds__(256) void inv_dft_kernel(
    const float* __restrict__ xm_r, const float* __restrict__ xm_i,
    const float2* __restrict__ tw, const int* __restrict__ rs,
    float* __restrict__ y, int T)
{
    __shared__ float2 Xv[16][360];
    __shared__ float2 twl[Ww];
    const int h = blockIdx.x;
    const int bcBase = blockIdx.y * 16;
    const int tid = threadIdx.x;
    const int tstart = rs[h];
    const int count = rs[h + 1] - tstart;
    for (int i = tid; i < Ww; i += 256) twl[i] = tw[i];
    const bool hasNyq = (count == NBINS);
    const int cnt = hasNyq ? 360 : count;  // bins stored in LDS (j=0..cnt-1)
    for (int idx = tid; idx < 16 * cnt; idx += 256) {
        int bcl = idx / cnt;
        int j = idx - bcl * cnt;
        size_t base = (size_t)(bcBase + bcl) * T + tstart;
        Xv[bcl][j] = make_float2(xm_r[base + j], xm_i[base + j]);
    }
    __syncthreads();
    const int bcl = tid >> 4;
    const int wl = tid & 15;
    float* yrow = y + (size_t)(bcBase + bcl) * HW + h * Ww;
    if (cnt <= 0) {
        for (int w = wl; w < Ww; w += 16) yrow[w] = 0.f;
        return;
    }
    float nyq = 0.f;
    if (hasNyq) nyq = xm_r[(size_t)(bcBase + bcl) * T + tstart + 360];
    for (int w = wl; w < NBINS; w += 16) {
        float cs = 0.f, ss = 0.f;
        int idx = w;
#pragma unroll 4
        for (int j = 1; j < cnt; ++j) {
            float2 Xj = Xv[bcl][j];
            float2 t = twl[idx];
            cs = fmaf(Xj.x, t.x, cs);
            ss = fmaf(Xj.y, t.y, ss);
            idx += w;
            idx = (idx >= Ww) ? idx - Ww : idx;
        }
        float b0 = Xv[bcl][0].x;
        float nf = (w & 1) ? -nyq : nyq;
        float a  = (b0 + nf + 2.f * (cs - ss)) * SCALE;
        float b2 = (b0 + nf + 2.f * (cs + ss)) * SCALE;
        yrow[w] = a;
        if (w != 0 && w != 360) yrow[Ww - w] = b2;
    }
}

// -------------------------------------------------- depthwise conv + add
__global__ __launch_bounds__(256) void conv_add_kernel(
    const float* __restrict__ y, const float* __restrict__ dw,
    float* __restrict__ out)
{
    int g = blockIdx.x * 256 + threadIdx.x;
    if (g >= Bb * Cc * HW) return;
    int w = g % Ww;
    int rem = g / Ww;
    int h = rem % Hh;
    int bc = rem / Hh;
    int c = bc & (Cc - 1);
    const float* yb = y + (size_t)bc * HW;
    int walt = (w >= Ww / 2) ? (w - Ww / 2) : (w + Ww / 2);
    float acc = yb[h * Ww + w];
#pragma unroll
    for (int k = 0; k < 11; ++k) {
        int hp = h + k - 5;
        int hh, ww;
        if (hp < 0)        { hh = -1 - hp;        ww = walt; }
        else if (hp >= Hh) { hh = 2 * Hh - 1 - hp; ww = walt; }
        else               { hh = hp;             ww = w; }
        acc = fmaf(dw[c * 11 + k], yb[hh * Ww + ww], acc);
    }
    out[g] = acc;
}

// ------------------------------------------------------------------ launch
extern "C" void kernel_launch(void* const* d_in, const int* in_sizes, int n_in,
                              void* d_out, int out_size, void* d_ws, size_t ws_size,
                              hipStream_t stream)
{
    const float* x      = (const float*)d_in[0];
    const float* mean_r = (const float*)d_in[1];
    const float* mean_i = (const float*)d_in[2];
    const float* stdv   = (const float*)d_in[3];
    const float* mags_r = (const float*)d_in[4];
    const float* mags_i = (const float*)d_in[5];
    const float* bias_r = (const float*)d_in[6];
    const float* bias_i = (const float*)d_in[7];
    const float* w1_r   = (const float*)d_in[8];
    const float* w1_i   = (const float*)d_in[9];
    const float* brelu  = (const float*)d_in[10];
    const float* w2_r   = (const float*)d_in[11];
    const float* w2_i   = (const float*)d_in[12];
    const float* glu_m  = (const float*)d_in[13];
    const float* glu_p  = (const float*)d_in[14];
    const float* dw     = (const float*)d_in[15];
    const int*   rows   = (const int*)d_in[16];
    const int T = in_sizes[16];

    char* ws = (char*)d_ws;
    size_t off = 0;
    float* y    = (float*)(ws + off); off += (size_t)Bb * Cc * HW * sizeof(float);
    float* xm_r = (float*)(ws + off); off += (size_t)Bb * Cc * T * sizeof(float);
    float* xm_i = (float*)(ws + off); off += (size_t)Bb * Cc * T * sizeof(float);
    off = (off + 255) & ~(size_t)255;
    float2* tw  = (float2*)(ws + off); off += (size_t)Ww * sizeof(float2);
    int* rs     = (int*)(ws + off);    off += (size_t)(Hh + 1) * sizeof(int);

    init_tw_kernel<<<3, 256, 0, stream>>>(tw);
    row_starts_kernel<<<2, 256, 0, stream>>>(rows, T, rs);
    fwd_dft_kernel<<<dim3(Hh, 8), 256, 0, stream>>>(x, tw, rs, xm_r, xm_i, T);
    const int nTile = (T + 31) / 32;
    middle_kernel<<<Bb * nTile, 256, 0, stream>>>(xm_r, xm_i, mean_r, mean_i, stdv,
        mags_r, mags_i, bias_r, bias_i, w1_r, w1_i, brelu, w2_r, w2_i,
        glu_m, glu_p, T, nTile);
    inv_dft_kernel<<<dim3(Hh, 8), 256, 0, stream>>>(xm_r, xm_i, tw, rs, y, T);
    conv_add_kernel<<<(Bb * Cc * HW + 255) / 256, 256, 0, stream>>>(y, dw, (float*)d_out);
}

// Round 3
// 1088.498 us; speedup vs baseline: 2.4451x; 2.4451x over previous
//
#include <hip/hip_runtime.h>
#include <hip/hip_bf16.h>
#include <math.h>

#define Hh 360
#define Ww 720
#define Cc 64
#define Bb 2
#define BC (Bb*Cc)        // 128
#define Mrows (BC*Hh)     // 46080
#define CHUNKS 4
#define CM (Mrows/CHUNKS) // 11520
#define KF3 1152          // fwd K: [hi|lo|hi] blocks of 384
#define NF 384            // fwd N (361 bins padded)
#define KI 768            // inv K: [Re(384) | Im(384)]
#define NI 768            // inv N alloc (720 used)
#define NSTORE_INV 720
#define SCALE 0.037267799624996496f   // 1/sqrt(720)
#define TWO_PI 6.2831853071795864769f

typedef __attribute__((ext_vector_type(8))) short s16x8;
typedef __attribute__((ext_vector_type(4))) float f32x4;
typedef __hip_bfloat16 bf16;

__device__ __forceinline__ void gload_lds16(const void* g, void* l) {
    __builtin_amdgcn_global_load_lds(
        (const __attribute__((address_space(1))) unsigned int*)g,
        (__attribute__((address_space(3))) unsigned int*)l, 16, 0, 0);
}

// ---------------------------------------------------------- B-matrix builds
// Fwd, K-extended: col blocks [0:384)=hi, [384:768)=hi, [768:1152)=lo of
// Bc[j][w] = SCALE*cos(2pi jw/720), Bs[j][w] = -SCALE*sin(2pi jw/720).
__global__ __launch_bounds__(256) void build_bfwd_kernel(bf16* __restrict__ Bc,
                                                         bf16* __restrict__ Bs) {
    int g = blockIdx.x * 256 + threadIdx.x;
    if (g >= NF * KF3) return;
    int wext = g % KF3;
    int j = g / KF3;
    int blk = wext / 384;
    int w = wext - blk * 384;
    float c = 0.f, s = 0.f;
    if (w <= 360 && j <= 360) {
        int idx = (j * w) % Ww;
        float a = (TWO_PI / Ww) * (float)idx;
        float sv, cv;
        sincosf(a, &sv, &cv);
        c = SCALE * cv;
        s = -SCALE * sv;
    }
    bf16 chi = __float2bfloat16(c);
    bf16 shi = __float2bfloat16(s);
    if (blk == 2) {
        Bc[g] = __float2bfloat16(c - __bfloat162float(chi));
        Bs[g] = __float2bfloat16(s - __bfloat162float(shi));
    } else {
        Bc[g] = chi;
        Bs[g] = shi;
    }
}

// Bt_inv[n][k]: n=output w (0..719); k<=360: j=k, f*SCALE*cos(2pi jn/720),
// f=1 for j=0/360 else 2; k in [384,744]: j=k-384, -2*SCALE*sin(2pi jn/720).
__global__ __launch_bounds__(256) void build_binv_kernel(bf16* __restrict__ Bi) {
    int g = blockIdx.x * 256 + threadIdx.x;
    if (g >= NI * KI) return;
    int k = g % KI, n = g / KI;
    float v = 0.f;
    if (n < NSTORE_INV) {
        if (k <= 360) {
            int j = k;
            float f = (j == 0 || j == 360) ? 1.f : 2.f;
            int idx = (j * n) % Ww;
            v = SCALE * f * cosf((TWO_PI / Ww) * (float)idx);
        } else if (k >= 384 && k <= 744) {
            int j = k - 384;
            int idx = (j * n) % Ww;
            v = -2.f * SCALE * sinf((TWO_PI / Ww) * (float)idx);
        }
    }
    Bi[g] = __float2bfloat16(v);
}

// --------------------------------------------- pack x chunk -> A_ext (p,q)
// A row layout: [0:384)=hi, [384:768)=lo, [768:1152)=hi.
__global__ __launch_bounds__(256) void pack_kernel(const float* __restrict__ x,
                                                   bf16* __restrict__ Ap,
                                                   bf16* __restrict__ Aq) {
    int g = blockIdx.x * 256 + threadIdx.x;
    if (g >= CM * KF3) return;
    int wext = g % KF3;
    int row = g / KF3;
    int blk = wext / 384;
    int w = wext - blk * 384;
    float p = 0.f, q = 0.f;
    if (w == 0 || w == 360) {
        p = x[(size_t)row * Ww + w];
    } else if (w < 360) {
        float a = x[(size_t)row * Ww + w];
        float b = x[(size_t)row * Ww + (Ww - w)];
        p = a + b;
        q = a - b;
    }
    bf16 phi = __float2bfloat16(p);
    bf16 qhi = __float2bfloat16(q);
    if (blk == 1) {
        Ap[g] = __float2bfloat16(p - __bfloat162float(phi));
        Aq[g] = __float2bfloat16(q - __bfloat162float(qhi));
    } else {
        Ap[g] = phi;
        Aq[g] = qhi;
    }
}

// ----------------------------------------------------------------- zero fill
__global__ __launch_bounds__(256) void fill_zero_kernel(uint4* __restrict__ p, long n) {
    long i = (long)blockIdx.x * 256 + threadIdx.x;
    long stride = (long)gridDim.x * 256;
    uint4 z = make_uint4(0u, 0u, 0u, 0u);
    for (; i < n; i += stride) p[i] = z;
}

// --------------------------------------------------------------- MFMA GEMM
// C[M][ldc](fp32) = A[M][K](bf16) * Bt[N][K](bf16)^T ; M mult of 128, K mult of 64.
__global__ __launch_bounds__(256) void gemm_bt_kernel(
    const bf16* __restrict__ A, const bf16* __restrict__ Bt,
    float* __restrict__ C, int K, int ldc, int nstore)
{
    __shared__ __align__(128) bf16 As[128][64];
    __shared__ __align__(128) bf16 Bs[128][64];
    const int tid = threadIdx.x;
    const int lane = tid & 63;
    const int wave = tid >> 6;
    const int m0 = blockIdx.x * 128;
    const int n0 = blockIdx.y * 128;
    const int wr = (wave >> 1) * 64;
    const int wc = (wave & 1) * 64;
    const int srow = tid >> 3;
    const int scol = (tid & 7) << 3;
    f32x4 acc[4][4] = {};
    for (int k0 = 0; k0 < K; k0 += 64) {
#pragma unroll
        for (int i = 0; i < 4; ++i) {
            const bf16* ga = A  + (size_t)(m0 + i * 32 + srow) * K + k0 + scol;
            const bf16* gb = Bt + (size_t)(n0 + i * 32 + srow) * K + k0 + scol;
            gload_lds16(ga, ((char*)&As[0][0]) + (size_t)(i * 256 + tid) * 16);
            gload_lds16(gb, ((char*)&Bs[0][0]) + (size_t)(i * 256 + tid) * 16);
        }
        __syncthreads();
#pragma unroll
        for (int kk = 0; kk < 64; kk += 32) {
            s16x8 a[4], b[4];
#pragma unroll
            for (int m = 0; m < 4; ++m)
                a[m] = *(const s16x8*)&As[wr + m * 16 + (lane & 15)][kk + (lane >> 4) * 8];
#pragma unroll
            for (int n = 0; n < 4; ++n)
                b[n] = *(const s16x8*)&Bs[wc + n * 16 + (lane & 15)][kk + (lane >> 4) * 8];
#pragma unroll
            for (int m = 0; m < 4; ++m)
#pragma unroll
                for (int n = 0; n < 4; ++n)
                    acc[m][n] = __builtin_amdgcn_mfma_f32_16x16x32_bf16(a[m], b[n], acc[m][n], 0, 0, 0);
        }
        __syncthreads();
    }
    const int rbase = (lane >> 4) * 4;
    const int cidx = lane & 15;
#pragma unroll
    for (int m = 0; m < 4; ++m) {
#pragma unroll
        for (int n = 0; n < 4; ++n) {
            int gcol = n0 + wc + n * 16 + cidx;
            if (gcol < nstore) {
#pragma unroll
                for (int r = 0; r < 4; ++r) {
                    int grow = m0 + wr + m * 16 + rbase + r;
                    C[(size_t)grow * ldc + gcol] = acc[m][n][r];
                }
            }
        }
    }
}

// ------------------------------------------------------------ middle stage
__device__ __forceinline__ float gelu_exact(float v) {
    return 0.5f * v * (1.0f + erff(v * 0.7071067811865476f));
}

__global__ __launch_bounds__(256) void middle_kernel(
    const float* __restrict__ Xre, const float* __restrict__ Xim,
    bf16* __restrict__ Ainv,
    const float* __restrict__ mean_r, const float* __restrict__ mean_i,
    const float* __restrict__ stdv,
    const float* __restrict__ mags_r, const float* __restrict__ mags_i,
    const float* __restrict__ bias_r, const float* __restrict__ bias_i,
    const float* __restrict__ w1_r, const float* __restrict__ w1_i,
    const float* __restrict__ brelu_p,
    const float* __restrict__ w2_r, const float* __restrict__ w2_i,
    const float* __restrict__ glu_mags, const float* __restrict__ glu_phases,
    const int* __restrict__ rows, const int* __restrict__ cols,
    int T, int nTile)
{
    __shared__ float2 W1[64 * 65];
    __shared__ float2 W2[64 * 65];
    __shared__ float2 hbuf[4][64];
    __shared__ float2 h2buf[4][64];
    const int tid = threadIdx.x;
    const int b = blockIdx.x / nTile;
    const int tile = blockIdx.x - b * nTile;
    const int t0 = tile * 32;
    for (int idx = tid; idx < 4096; idx += 256) {
        int i = idx & 63;
        int o = idx >> 6;
        W1[i * 65 + o] = make_float2(w1_r[o * 64 + i], w1_i[o * 64 + i]);
        W2[i * 65 + o] = make_float2(w2_r[o * 64 + i], w2_i[o * 64 + i]);
    }
    const float brelu = brelu_p[0];
    const int o = tid & 63;
    const int tl = tid >> 6;
    __syncthreads();
    for (int tt = 0; tt < 32; tt += 4) {
        const int t = t0 + tt + tl;
        const bool valid = (t < T);
        float xr = 0.f, xi = 0.f;
        int h = 0, j = 0;
        float2 h1 = make_float2(0.f, 0.f);
        if (valid) {
            h = rows[t]; j = cols[t];
            size_t ridx = ((size_t)(b * Cc + o) * Hh + h) * NF + j;
            xr = Xre[ridx];
            xi = Xim[ridx];
            float inv = 1.0f / (1e-12f + stdv[t]);
            float hr = (xr - mean_r[t]) * inv;
            float hi2 = (xi - mean_i[t]) * inv;
            float mr = mags_r[o], mi = mags_i[o];
            h1.x = fmaf(hr, mr, fmaf(-hi2, mi, bias_r[o]));
            h1.y = fmaf(hr, mi, fmaf(hi2, mr, bias_i[o]));
        }
        hbuf[tl][o] = h1;
        __syncthreads();
        float ar = 0.f, ai = 0.f;
#pragma unroll 8
        for (int i = 0; i < 64; ++i) {
            float2 wv = W1[i * 65 + o];
            float2 hv = hbuf[tl][i];
            ar = fmaf(wv.x, hv.x, ar); ar = fmaf(-wv.y, hv.y, ar);
            ai = fmaf(wv.x, hv.y, ai); ai = fmaf(wv.y, hv.x, ai);
        }
        float r = sqrtf(ar * ar + ai * ai);
        float g = gelu_exact(r + brelu);
        float2 h2;
        if (r > 0.f) { float f = g / r; h2 = make_float2(f * ar, f * ai); }
        else h2 = make_float2(g, 0.f);
        h2buf[tl][o] = h2;
        __syncthreads();
        float cr = 0.f, ci = 0.f;
#pragma unroll 8
        for (int i = 0; i < 64; ++i) {
            float2 wv = W2[i * 65 + o];
            float2 hv = h2buf[tl][i];
            cr = fmaf(wv.x, hv.x, cr); cr = fmaf(-wv.y, hv.y, cr);
            ci = fmaf(wv.x, hv.y, ci); ci = fmaf(wv.y, hv.x, ci);
        }
        if (valid) {
            float r3 = sqrtf(cr * cr + ci * ci);
            float gm = glu_mags[(size_t)o * T + t];
            float gp = glu_phases[(size_t)o * T + t];
            float sg = 1.0f / (1.0f + expf(-(r3 + gm)));
            float ux, uy;
            if (r3 > 0.f) { float ir3 = 1.0f / r3; ux = cr * ir3; uy = ci * ir3; }
            else { ux = 1.f; uy = 0.f; }
            float sp, cp;
            sincosf(gp, &sp, &cp);
            float gx = sg * (ux * cp - uy * sp);
            float gy = sg * (ux * sp + uy * cp);
            size_t widx = ((size_t)(b * Cc + o) * Hh + h) * KI + j;
            Ainv[widx]       = __float2bfloat16(xr * gx - xi * gy);
            Ainv[widx + 384] = __float2bfloat16(xr * gy + xi * gx);
        }
        __syncthreads();
    }
}

// -------------------------------------------------- depthwise conv + add
__global__ __launch_bounds__(256) void conv_add_kernel(
    const float* __restrict__ y, const float* __restrict__ dw,
    float* __restrict__ out)
{
    int g = blockIdx.x * 256 + threadIdx.x;
    if (g >= Bb * Cc * Hh * Ww) return;
    int w = g % Ww;
    int rem = g / Ww;
    int h = rem % Hh;
    int bc = rem / Hh;
    int c = bc & (Cc - 1);
    const float* yb = y + (size_t)bc * Hh * NI;
    int walt = (w >= Ww / 2) ? (w - Ww / 2) : (w + Ww / 2);
    float acc = yb[h * NI + w];
#pragma unroll
    for (int k = 0; k < 11; ++k) {
        int hp = h + k - 5;
        int hh, ww;
        if (hp < 0)        { hh = -1 - hp;         ww = walt; }
        else if (hp >= Hh) { hh = 2 * Hh - 1 - hp; ww = walt; }
        else               { hh = hp;              ww = w; }
        acc = fmaf(dw[c * 11 + k], yb[hh * NI + ww], acc);
    }
    out[g] = acc;
}

// ------------------------------------------------------------------ launch
extern "C" void kernel_launch(void* const* d_in, const int* in_sizes, int n_in,
                              void* d_out, int out_size, void* d_ws, size_t ws_size,
                              hipStream_t stream)
{
    const float* x      = (const float*)d_in[0];
    const float* mean_r = (const float*)d_in[1];
    const float* mean_i = (const float*)d_in[2];
    const float* stdv   = (const float*)d_in[3];
    const float* mags_r = (const float*)d_in[4];
    const float* mags_i = (const float*)d_in[5];
    const float* bias_r = (const float*)d_in[6];
    const float* bias_i = (const float*)d_in[7];
    const float* w1_r   = (const float*)d_in[8];
    const float* w1_i   = (const float*)d_in[9];
    const float* brelu  = (const float*)d_in[10];
    const float* w2_r   = (const float*)d_in[11];
    const float* w2_i   = (const float*)d_in[12];
    const float* glu_m  = (const float*)d_in[13];
    const float* glu_p  = (const float*)d_in[14];
    const float* dw     = (const float*)d_in[15];
    const int*   rows   = (const int*)d_in[16];
    const int*   cols   = (const int*)d_in[17];
    const int T = in_sizes[16];

    char* ws = (char*)d_ws;
    // Layout (total 213.5 MB, <= proven-safe 214.1):
    //   [0, 26.5M)      A chunk p (CM x KF3 bf16)
    //   [26.5M, 53.1M)  A chunk q
    //   [53.1M, 54.8M)  Bc_ext, Bs_ext (dead before Ainv zero-fill)
    //   [0, 70.8M)      Ainv (after fwd phase)
    //   [70.8M, 212.3M) Xre, Xim fp32  -> later y fp32 [Mrows][NI]
    //   [212.3M, ...)   Binv
    const size_t SApc = (size_t)CM * KF3 * 2;          // 26,542,080
    bf16* Ap    = (bf16*)ws;
    bf16* Aq    = (bf16*)(ws + SApc);
    bf16* Bce   = (bf16*)(ws + 2 * SApc);
    bf16* Bse   = (bf16*)(ws + 2 * SApc + (size_t)NF * KF3 * 2);
    bf16* Ainv  = (bf16*)ws;                           // 70,778,880 B
    const size_t SAinv = (size_t)Mrows * KI * 2;
    float* Xre  = (float*)(ws + SAinv);
    float* Xim  = (float*)(ws + SAinv + (size_t)Mrows * NF * 4);
    float* y    = (float*)(ws + SAinv);                // [Mrows][NI] fp32
    bf16* Bti   = (bf16*)(ws + SAinv + 2 * (size_t)Mrows * NF * 4);

    build_bfwd_kernel<<<(NF * KF3 + 255) / 256, 256, 0, stream>>>(Bce, Bse);
    build_binv_kernel<<<(NI * KI + 255) / 256, 256, 0, stream>>>(Bti);

    for (int c = 0; c < CHUNKS; ++c) {
        pack_kernel<<<(CM * KF3 + 255) / 256, 256, 0, stream>>>(
            x + (size_t)c * CM * Ww, Ap, Aq);
        gemm_bt_kernel<<<dim3(CM / 128, NF / 128), 256, 0, stream>>>(
            Ap, Bce, Xre + (size_t)c * CM * NF, KF3, NF, NF);
        gemm_bt_kernel<<<dim3(CM / 128, NF / 128), 256, 0, stream>>>(
            Aq, Bse, Xim + (size_t)c * CM * NF, KF3, NF, NF);
    }

    fill_zero_kernel<<<2048, 256, 0, stream>>>((uint4*)Ainv, (long)(SAinv / 16));

    const int nTile = (T + 31) / 32;
    middle_kernel<<<Bb * nTile, 256, 0, stream>>>(Xre, Xim, Ainv,
        mean_r, mean_i, stdv, mags_r, mags_i, bias_r, bias_i,
        w1_r, w1_i, brelu, w2_r, w2_i, glu_m, glu_p, rows, cols, T, nTile);

    gemm_bt_kernel<<<dim3(Mrows / 128, NI / 128), 256, 0, stream>>>(
        Ainv, Bti, y, KI, NI, NSTORE_INV);

    conv_add_kernel<<<(Bb * Cc * Hh * Ww + 255) / 256, 256, 0, stream>>>(y, dw, (float*)d_out);
}